// Round 3
// baseline (323.133 us; speedup 1.0000x reference)
//
#include <hip/hip_runtime.h>
#include <math.h>
#include <stdint.h>

// MoE gate: gate = inp[16384,2048]f32 @ W[64,2048]^T + b[64]; top-2; softmax.
// d_out (float32): [tokens*2] indices-as-floats, then [tokens*2] scores.
//
// Round 3: LDS-traffic analysis showed the 4x4-tile GEMM was LDS-bound
// (2 B LDS per FMA -> 3x over VALU). New structure: lane owns 1 token x 64
// experts (acc[64] VGPRs); A read once from LDS per 64 FMAs; W via uniform
// (scalar) loads from a pre-transposed Wt[k][64] -> near-zero LDS traffic.

#define KDIM 2048
#define NEXP 64
#define TPB  256          // tokens per block == threads per block (gemm)
#define BK   32           // k per LDS tile
#define LDST (BK + 4)     // pad to 36 floats: b128-aligned, breaks worst conflicts

// ---------------- W transpose: W[64][2048] -> Wt[2048][64] ----------------
__global__ __launch_bounds__(256) void transpose_w_kernel(
    const float* __restrict__ W, float* __restrict__ Wt)
{
    const int idx = blockIdx.x * 256 + threadIdx.x;   // 131072 total
    const int e = idx >> 11;        // expert 0..63
    const int k = idx & 2047;      // k 0..2047
    Wt[k * NEXP + e] = W[idx];     // coalesced read, scattered 512KB write
}

// ---------------- GEMM partial: per-lane token, 64-expert accumulator -----
__global__ __launch_bounds__(256) void gate_partial_kernel(
    const float* __restrict__ inp,
    const float* __restrict__ Wt,      // [KDIM][NEXP]
    float* __restrict__ partial,       // [S][tokens][NEXP]
    int tokens, int kPerSplit)
{
    __shared__ float As[TPB * LDST];   // [token][k] padded, 36 KB

    const int tid     = threadIdx.x;
    const int tokBase = blockIdx.x * TPB;
    const int split   = blockIdx.y;
    const int k0      = split * kPerSplit;

    // staging map: thread t loads rows (t>>3)+32p, cols (t&7)*4 (float4),
    // 8 passes -> 256 tokens x 32 k. 8 lanes x 16B = 128B contiguous/row.
    const int srow = tid >> 3;
    const int scol = (tid & 7) << 2;
    const float* aBase = inp + (size_t)tokBase * KDIM + k0;

    float4 stage[8];
    #pragma unroll
    for (int p = 0; p < 8; ++p)
        stage[p] = *(const float4*)(aBase + (size_t)(srow + 32 * p) * KDIM + scol);

    float acc[NEXP];
    #pragma unroll
    for (int e = 0; e < NEXP; ++e) acc[e] = 0.0f;

    const int NT = kPerSplit / BK;
    for (int kt = 0; kt < NT; ++kt) {
        __syncthreads();   // previous tile's reads done
        #pragma unroll
        for (int p = 0; p < 8; ++p)
            *(float4*)&As[(srow + 32 * p) * LDST + scol] = stage[p];
        __syncthreads();
        if (kt + 1 < NT) {
            const int koff = (kt + 1) * BK;
            #pragma unroll
            for (int p = 0; p < 8; ++p)
                stage[p] = *(const float4*)(aBase + (size_t)(srow + 32 * p) * KDIM + koff + scol);
        }
        // W row pointer for this tile (uniform address -> scalar loads)
        const float* __restrict__ wTile = Wt + (size_t)(k0 + kt * BK) * NEXP;
        #pragma unroll
        for (int kq = 0; kq < BK / 4; ++kq) {
            const float4 a4 = *(const float4*)&As[tid * LDST + (kq << 2)];
            #pragma unroll
            for (int j = 0; j < 4; ++j) {
                const float a = (j == 0) ? a4.x : (j == 1) ? a4.y : (j == 2) ? a4.z : a4.w;
                const float* __restrict__ wr = wTile + ((kq << 2) + j) * NEXP;
                #pragma unroll
                for (int e = 0; e < NEXP; ++e)
                    acc[e] = fmaf(a, wr[e], acc[e]);
            }
        }
    }

    // write partials: lane owns token tokBase+tid, 64 floats contiguous
    float* p = partial + ((size_t)split * tokens + tokBase + tid) * NEXP;
    #pragma unroll
    for (int e = 0; e < NEXP; e += 4)
        *(float4*)&p[e] = make_float4(acc[e], acc[e + 1], acc[e + 2], acc[e + 3]);
}

// ---------------- reduce over splits + bias + top-2 + softmax -------------
__global__ __launch_bounds__(256) void reduce_topk_kernel(
    const float* __restrict__ partial,
    const float* __restrict__ bias,
    float* __restrict__ out,
    int tokens, int S)
{
    const int tid = threadIdx.x;
    const int tx  = tid & 15;          // experts 4*tx..4*tx+3
    const int ty  = tid >> 4;          // 16 tokens per block
    const int token = blockIdx.x * 16 + ty;
    const int eBase = tx << 2;

    float4 v = make_float4(0.f, 0.f, 0.f, 0.f);
    for (int s = 0; s < S; ++s) {
        const float4 p = *(const float4*)&partial[((size_t)s * tokens + token) * NEXP + eBase];
        v.x += p.x; v.y += p.y; v.z += p.z; v.w += p.w;
    }
    const float4 bv = *(const float4*)&bias[eBase];
    float g[4] = { v.x + bv.x, v.y + bv.y, v.z + bv.z, v.w + bv.w };

    // local top-2 (ascending scan keeps lower index on ties, matching lax.top_k)
    float v1 = g[0]; int i1 = eBase;
    float v2 = -INFINITY; int i2 = -1;
    #pragma unroll
    for (int c = 1; c < 4; ++c) {
        const float vv = g[c];
        const int   ii = eBase + c;
        if (vv > v1)      { v2 = v1; i2 = i1; v1 = vv; i1 = ii; }
        else if (vv > v2) { v2 = vv; i2 = ii; }
    }
    // 16-lane butterfly merge
    #pragma unroll
    for (int m = 1; m <= 8; m <<= 1) {
        const float ov1 = __shfl_xor(v1, m);
        const int   oi1 = __shfl_xor(i1, m);
        const float ov2 = __shfl_xor(v2, m);
        const int   oi2 = __shfl_xor(i2, m);
        const bool aw = (v1 > ov1) || (v1 == ov1 && i1 < oi1);
        const float nv1 = aw ? v1  : ov1;  const int ni1 = aw ? i1  : oi1;
        const float lv  = aw ? ov1 : v1;   const int li  = aw ? oi1 : i1;
        const float sv  = aw ? v2  : ov2;  const int si  = aw ? i2  : oi2;
        const bool sw = (sv > lv) || (sv == lv && si < li);
        v1 = nv1; i1 = ni1;
        v2 = sw ? sv : lv; i2 = sw ? si : li;
    }
    if (tx == 0) {
        const float e2 = expf(v2 - v1);
        const float denom = 1.0f + e2;
        out[2 * token]     = (float)i1;
        out[2 * token + 1] = (float)i2;
        out[tokens * 2 + 2 * token]     = 1.0f / denom;
        out[tokens * 2 + 2 * token + 1] = e2 / denom;
    }
}

extern "C" void kernel_launch(void* const* d_in, const int* in_sizes, int n_in,
                              void* d_out, int out_size, void* d_ws, size_t ws_size,
                              hipStream_t stream) {
    const float* inp  = (const float*)d_in[0];
    const float* W    = (const float*)d_in[1];
    const float* bias = (const float*)d_in[2];
    float* out = (float*)d_out;

    const int tokens = in_sizes[0] / KDIM;   // 16384

    // pick largest split S in {8,4,2,1} fitting partials + Wt in d_ws
    int S = 8;
    while (S > 1 &&
           (size_t)S * tokens * NEXP * sizeof(float) + (size_t)KDIM * NEXP * sizeof(float) > ws_size)
        S >>= 1;
    const int kPerSplit = KDIM / S;

    float* partial = (float*)d_ws;
    float* Wt = partial + (size_t)S * tokens * NEXP;

    transpose_w_kernel<<<(NEXP * KDIM) / 256, 256, 0, stream>>>(W, Wt);

    dim3 grid(tokens / TPB, S);
    gate_partial_kernel<<<grid, 256, 0, stream>>>(inp, Wt, partial, tokens, kPerSplit);

    reduce_topk_kernel<<<tokens / 16, 256, 0, stream>>>(partial, bias, out, tokens, S);
}

// Round 4
// 306.692 us; speedup vs baseline: 1.0536x; 1.0536x over previous
//
#include <hip/hip_runtime.h>
#include <math.h>

// MoE gate: gate = inp[16384,2048]f32 @ W[64,2048]^T + b[64]; top-2; softmax.
// d_out (float32): [tokens*2] indices-as-floats, then [tokens*2] scores.
//
// Round 4: round-3 structure (lane = 1 token x 64 experts, W via scalar
// loads from transposed Wt) was right but acc[64] SPILLED (VGPR_Count=60,
// +120MB scratch traffic). Fix: __launch_bounds__(256,2) -> VGPR cap 256,
// and BK=16 so staging is only 4 float4 regs. ~110 VGPRs, no spill.

#define KDIM 2048
#define NEXP 64
#define TPB  256          // tokens per block == threads per block (gemm)
#define BK   16           // k per LDS tile
#define LDST (BK + 4)     // 20 floats = 80 B row stride: 16B-aligned, conflict-light

// ---------------- W transpose: W[64][2048] -> Wt[2048][64] ----------------
__global__ __launch_bounds__(256) void transpose_w_kernel(
    const float* __restrict__ W, float* __restrict__ Wt)
{
    const int idx = blockIdx.x * 256 + threadIdx.x;   // 131072 total
    const int e = idx >> 11;       // expert 0..63
    const int k = idx & 2047;      // k 0..2047
    Wt[k * NEXP + e] = W[idx];
}

// ---------------- GEMM partial: per-lane token, 64-expert accumulator -----
// // launch_bounds(256,2): 2 waves/EU min -> 2 blocks/CU, VGPR cap 256.
// // Without it the backend targeted high occupancy and spilled acc[64] (R3).
__global__ __launch_bounds__(256, 2) void gate_partial_kernel(
    const float* __restrict__ inp,
    const float* __restrict__ Wt,      // [KDIM][NEXP]
    float* __restrict__ partial,       // [S][tokens][NEXP]
    int tokens, int kPerSplit)
{
    __shared__ float As[TPB * LDST];   // [token][k] padded, 20 KB

    const int tid     = threadIdx.x;
    const int tokBase = blockIdx.x * TPB;
    const int split   = blockIdx.y;
    const int k0      = split * kPerSplit;

    // staging map: 256 tokens x 16 k per tile; thread t covers row (t>>2)+64p,
    // cols (t&3)*4..+3 (float4). 4 lanes = 64 B contiguous per row.
    const int srow = tid >> 2;          // 0..63
    const int scol = (tid & 3) << 2;    // 0,4,8,12
    const float* aBase = inp + (size_t)tokBase * KDIM + k0;

    float4 stage[4];
    #pragma unroll
    for (int p = 0; p < 4; ++p)
        stage[p] = *(const float4*)(aBase + (size_t)(srow + 64 * p) * KDIM + scol);

    float acc[NEXP];
    #pragma unroll
    for (int e = 0; e < NEXP; ++e) acc[e] = 0.0f;

    const int NT = kPerSplit / BK;
    for (int kt = 0; kt < NT; ++kt) {
        __syncthreads();   // previous tile's reads done
        #pragma unroll
        for (int p = 0; p < 4; ++p)
            *(float4*)&As[(srow + 64 * p) * LDST + scol] = stage[p];
        __syncthreads();
        if (kt + 1 < NT) {
            const int koff = (kt + 1) * BK;
            #pragma unroll
            for (int p = 0; p < 4; ++p)
                stage[p] = *(const float4*)(aBase + (size_t)(srow + 64 * p) * KDIM + koff + scol);
        }
        // W rows for this tile: uniform addresses -> scalar (s_load) pipe
        const float* __restrict__ wTile = Wt + (size_t)(k0 + kt * BK) * NEXP;
        #pragma unroll
        for (int kq = 0; kq < BK / 4; ++kq) {
            const float4 a4 = *(const float4*)&As[tid * LDST + (kq << 2)];
            #pragma unroll
            for (int j = 0; j < 4; ++j) {
                const float a = (j == 0) ? a4.x : (j == 1) ? a4.y : (j == 2) ? a4.z : a4.w;
                const float* __restrict__ wr = wTile + ((kq << 2) + j) * NEXP;
                #pragma unroll
                for (int e = 0; e < NEXP; ++e)
                    acc[e] = fmaf(a, wr[e], acc[e]);
            }
        }
    }

    // write partials: lane owns token tokBase+tid, 64 floats contiguous
    float* p = partial + ((size_t)split * tokens + tokBase + tid) * NEXP;
    #pragma unroll
    for (int e = 0; e < NEXP; e += 4)
        *(float4*)&p[e] = make_float4(acc[e], acc[e + 1], acc[e + 2], acc[e + 3]);
}

// ---------------- reduce over splits + bias + top-2 + softmax -------------
__global__ __launch_bounds__(256) void reduce_topk_kernel(
    const float* __restrict__ partial,
    const float* __restrict__ bias,
    float* __restrict__ out,
    int tokens, int S)
{
    const int tid = threadIdx.x;
    const int tx  = tid & 15;          // experts 4*tx..4*tx+3
    const int ty  = tid >> 4;          // 16 tokens per block
    const int token = blockIdx.x * 16 + ty;
    const int eBase = tx << 2;

    float4 v = make_float4(0.f, 0.f, 0.f, 0.f);
    for (int s = 0; s < S; ++s) {
        const float4 p = *(const float4*)&partial[((size_t)s * tokens + token) * NEXP + eBase];
        v.x += p.x; v.y += p.y; v.z += p.z; v.w += p.w;
    }
    const float4 bv = *(const float4*)&bias[eBase];
    float g[4] = { v.x + bv.x, v.y + bv.y, v.z + bv.z, v.w + bv.w };

    // local top-2 (ascending scan keeps lower index on ties, matching lax.top_k)
    float v1 = g[0]; int i1 = eBase;
    float v2 = -INFINITY; int i2 = -1;
    #pragma unroll
    for (int c = 1; c < 4; ++c) {
        const float vv = g[c];
        const int   ii = eBase + c;
        if (vv > v1)      { v2 = v1; i2 = i1; v1 = vv; i1 = ii; }
        else if (vv > v2) { v2 = vv; i2 = ii; }
    }
    // 16-lane butterfly merge
    #pragma unroll
    for (int m = 1; m <= 8; m <<= 1) {
        const float ov1 = __shfl_xor(v1, m);
        const int   oi1 = __shfl_xor(i1, m);
        const float ov2 = __shfl_xor(v2, m);
        const int   oi2 = __shfl_xor(i2, m);
        const bool aw = (v1 > ov1) || (v1 == ov1 && i1 < oi1);
        const float nv1 = aw ? v1  : ov1;  const int ni1 = aw ? i1  : oi1;
        const float lv  = aw ? ov1 : v1;   const int li  = aw ? oi1 : i1;
        const float sv  = aw ? v2  : ov2;  const int si  = aw ? i2  : oi2;
        const bool sw = (sv > lv) || (sv == lv && si < li);
        v1 = nv1; i1 = ni1;
        v2 = sw ? sv : lv; i2 = sw ? si : li;
    }
    if (tx == 0) {
        const float e2 = expf(v2 - v1);
        const float denom = 1.0f + e2;
        out[2 * token]     = (float)i1;
        out[2 * token + 1] = (float)i2;
        out[tokens * 2 + 2 * token]     = 1.0f / denom;
        out[tokens * 2 + 2 * token + 1] = e2 / denom;
    }
}

extern "C" void kernel_launch(void* const* d_in, const int* in_sizes, int n_in,
                              void* d_out, int out_size, void* d_ws, size_t ws_size,
                              hipStream_t stream) {
    const float* inp  = (const float*)d_in[0];
    const float* W    = (const float*)d_in[1];
    const float* bias = (const float*)d_in[2];
    float* out = (float*)d_out;

    const int tokens = in_sizes[0] / KDIM;   // 16384

    // pick largest split S in {8,4,2,1} fitting partials + Wt in d_ws
    int S = 8;
    while (S > 1 &&
           (size_t)S * tokens * NEXP * sizeof(float) + (size_t)KDIM * NEXP * sizeof(float) > ws_size)
        S >>= 1;
    const int kPerSplit = KDIM / S;

    float* partial = (float*)d_ws;
    float* Wt = partial + (size_t)S * tokens * NEXP;

    transpose_w_kernel<<<(NEXP * KDIM) / 256, 256, 0, stream>>>(W, Wt);

    dim3 grid(tokens / TPB, S);
    gate_partial_kernel<<<grid, 256, 0, stream>>>(inp, Wt, partial, tokens, kPerSplit);

    reduce_topk_kernel<<<tokens / 16, 256, 0, stream>>>(partial, bias, out, tokens, S);
}

// Round 5
// 293.994 us; speedup vs baseline: 1.0991x; 1.0432x over previous
//
#include <hip/hip_runtime.h>
#include <math.h>

// MoE gate: gate = inp[16384,2048]f32 @ W[64,2048]^T + b[64]; top-2; softmax.
// d_out (float32): [tokens*2] indices-as-floats, then [tokens*2] scores.
//
// Round 5: R3/R4 spilled acc[64] (VGPR=60, +108MB scratch eviction at HBM)
// because the backend's occupancy TARGET stayed at 8 waves/EU (needs <=64
// VGPR); __launch_bounds__' 2nd arg only sets a cap, not the target.
// Fix: amdgpu_waves_per_eu(2,2) pins target occupancy -> VGPR budget 256,
// acc[64] stays in registers.

#define KDIM 2048
#define NEXP 64
#define TPB  256          // tokens per block == threads per block (gemm)
#define BK   16           // k per LDS tile
#define LDST (BK + 4)     // 20 floats = 80 B row stride: 16B-aligned, conflict-light

// ---------------- W transpose: W[64][2048] -> Wt[2048][64] ----------------
__global__ __launch_bounds__(256) void transpose_w_kernel(
    const float* __restrict__ W, float* __restrict__ Wt)
{
    const int idx = blockIdx.x * 256 + threadIdx.x;   // 131072 total
    const int e = idx >> 11;       // expert 0..63
    const int k = idx & 2047;      // k 0..2047
    Wt[k * NEXP + e] = W[idx];
}

// ---------------- GEMM partial: per-lane token, 64-expert accumulator -----
// waves_per_eu(2,2): pin occupancy target to 2 waves/EU (= our actual grid
// occupancy: 512 blocks, 2 blocks/CU). VGPR budget 256 -> no spill of acc[64].
__global__ __launch_bounds__(256)
__attribute__((amdgpu_waves_per_eu(2, 2)))
void gate_partial_kernel(
    const float* __restrict__ inp,
    const float* __restrict__ Wt,      // [KDIM][NEXP]
    float* __restrict__ partial,       // [S][tokens][NEXP]
    int tokens, int kPerSplit)
{
    __shared__ float As[TPB * LDST];   // [token][k] padded, 20 KB

    const int tid     = threadIdx.x;
    const int tokBase = blockIdx.x * TPB;
    const int split   = blockIdx.y;
    const int k0      = split * kPerSplit;

    // staging map: 256 tokens x 16 k per tile; thread t covers row (t>>2)+64p,
    // cols (t&3)*4..+3 (float4). 4 lanes = 64 B contiguous per row.
    const int srow = tid >> 2;          // 0..63
    const int scol = (tid & 3) << 2;    // 0,4,8,12
    const float* aBase = inp + (size_t)tokBase * KDIM + k0;

    float4 stage[4];
    #pragma unroll
    for (int p = 0; p < 4; ++p)
        stage[p] = *(const float4*)(aBase + (size_t)(srow + 64 * p) * KDIM + scol);

    float acc[NEXP];
    #pragma unroll
    for (int e = 0; e < NEXP; ++e) acc[e] = 0.0f;

    const int NT = kPerSplit / BK;
    for (int kt = 0; kt < NT; ++kt) {
        __syncthreads();   // previous tile's reads done
        #pragma unroll
        for (int p = 0; p < 4; ++p)
            *(float4*)&As[(srow + 64 * p) * LDST + scol] = stage[p];
        __syncthreads();
        if (kt + 1 < NT) {
            const int koff = (kt + 1) * BK;
            #pragma unroll
            for (int p = 0; p < 4; ++p)
                stage[p] = *(const float4*)(aBase + (size_t)(srow + 64 * p) * KDIM + koff + scol);
        }
        // W rows for this tile: uniform addresses -> scalar (s_load) pipe
        const float* __restrict__ wTile = Wt + (size_t)(k0 + kt * BK) * NEXP;
        #pragma unroll
        for (int kq = 0; kq < BK / 4; ++kq) {
            const float4 a4 = *(const float4*)&As[tid * LDST + (kq << 2)];
            #pragma unroll
            for (int j = 0; j < 4; ++j) {
                const float a = (j == 0) ? a4.x : (j == 1) ? a4.y : (j == 2) ? a4.z : a4.w;
                const float* __restrict__ wr = wTile + ((kq << 2) + j) * NEXP;
                #pragma unroll
                for (int e = 0; e < NEXP; ++e)
                    acc[e] = fmaf(a, wr[e], acc[e]);
            }
        }
    }

    // write partials: lane owns token tokBase+tid, 64 floats contiguous
    float* p = partial + ((size_t)split * tokens + tokBase + tid) * NEXP;
    #pragma unroll
    for (int e = 0; e < NEXP; e += 4)
        *(float4*)&p[e] = make_float4(acc[e], acc[e + 1], acc[e + 2], acc[e + 3]);
}

// ---------------- reduce over splits + bias + top-2 + softmax -------------
__global__ __launch_bounds__(256) void reduce_topk_kernel(
    const float* __restrict__ partial,
    const float* __restrict__ bias,
    float* __restrict__ out,
    int tokens, int S)
{
    const int tid = threadIdx.x;
    const int tx  = tid & 15;          // experts 4*tx..4*tx+3
    const int ty  = tid >> 4;          // 16 tokens per block
    const int token = blockIdx.x * 16 + ty;
    const int eBase = tx << 2;

    float4 v = make_float4(0.f, 0.f, 0.f, 0.f);
    for (int s = 0; s < S; ++s) {
        const float4 p = *(const float4*)&partial[((size_t)s * tokens + token) * NEXP + eBase];
        v.x += p.x; v.y += p.y; v.z += p.z; v.w += p.w;
    }
    const float4 bv = *(const float4*)&bias[eBase];
    float g[4] = { v.x + bv.x, v.y + bv.y, v.z + bv.z, v.w + bv.w };

    // local top-2 (ascending scan keeps lower index on ties, matching lax.top_k)
    float v1 = g[0]; int i1 = eBase;
    float v2 = -INFINITY; int i2 = -1;
    #pragma unroll
    for (int c = 1; c < 4; ++c) {
        const float vv = g[c];
        const int   ii = eBase + c;
        if (vv > v1)      { v2 = v1; i2 = i1; v1 = vv; i1 = ii; }
        else if (vv > v2) { v2 = vv; i2 = ii; }
    }
    // 16-lane butterfly merge
    #pragma unroll
    for (int m = 1; m <= 8; m <<= 1) {
        const float ov1 = __shfl_xor(v1, m);
        const int   oi1 = __shfl_xor(i1, m);
        const float ov2 = __shfl_xor(v2, m);
        const int   oi2 = __shfl_xor(i2, m);
        const bool aw = (v1 > ov1) || (v1 == ov1 && i1 < oi1);
        const float nv1 = aw ? v1  : ov1;  const int ni1 = aw ? i1  : oi1;
        const float lv  = aw ? ov1 : v1;   const int li  = aw ? oi1 : i1;
        const float sv  = aw ? v2  : ov2;  const int si  = aw ? i2  : oi2;
        const bool sw = (sv > lv) || (sv == lv && si < li);
        v1 = nv1; i1 = ni1;
        v2 = sw ? sv : lv; i2 = sw ? si : li;
    }
    if (tx == 0) {
        const float e2 = expf(v2 - v1);
        const float denom = 1.0f + e2;
        out[2 * token]     = (float)i1;
        out[2 * token + 1] = (float)i2;
        out[tokens * 2 + 2 * token]     = 1.0f / denom;
        out[tokens * 2 + 2 * token + 1] = e2 / denom;
    }
}

extern "C" void kernel_launch(void* const* d_in, const int* in_sizes, int n_in,
                              void* d_out, int out_size, void* d_ws, size_t ws_size,
                              hipStream_t stream) {
    const float* inp  = (const float*)d_in[0];
    const float* W    = (const float*)d_in[1];
    const float* bias = (const float*)d_in[2];
    float* out = (float*)d_out;

    const int tokens = in_sizes[0] / KDIM;   // 16384

    // pick largest split S in {8,4,2,1} fitting partials + Wt in d_ws
    int S = 8;
    while (S > 1 &&
           (size_t)S * tokens * NEXP * sizeof(float) + (size_t)KDIM * NEXP * sizeof(float) > ws_size)
        S >>= 1;
    const int kPerSplit = KDIM / S;

    float* partial = (float*)d_ws;
    float* Wt = partial + (size_t)S * tokens * NEXP;

    transpose_w_kernel<<<(NEXP * KDIM) / 256, 256, 0, stream>>>(W, Wt);

    dim3 grid(tokens / TPB, S);
    gate_partial_kernel<<<grid, 256, 0, stream>>>(inp, Wt, partial, tokens, kPerSplit);

    reduce_topk_kernel<<<tokens / 16, 256, 0, stream>>>(partial, bias, out, tokens, S);
}

// Round 6
// 265.046 us; speedup vs baseline: 1.2192x; 1.1092x over previous
//
#include <hip/hip_runtime.h>
#include <math.h>

// MoE gate: gate = inp[16384,2048]f32 @ W[64,2048]^T + b[64]; top-2; softmax.
// d_out (float32): [tokens*2] indices-as-floats, then [tokens*2] scores.
//
// Round 6: R5 fixed the spill (VGPR 88, WRITE=partials only) but VALUBusy
// stayed 18.5% = pure fp32 FMA floor diluted ~5x by serialized s_load (W)
// latency: <1 W row fits in SGPRs, so each 16-FMA chunk waits ~120cyc sK$.
// waves_per_eu(2,2) capped us at 2 waves/EU -> nothing to hide the stall.
// Fix: S=16 (1024 blocks = 4 blocks/CU = 4 waves/EU, issue-saturating) and
// waves_per_eu(2,4) (keeps 256-VGPR budget so acc[64] stays resident).

#define KDIM 2048
#define NEXP 64
#define TPB  256          // tokens per block == threads per block (gemm)
#define BK   16           // k per LDS tile
#define LDST (BK + 4)     // 20 floats = 80 B row stride (16B-aligned float4 reads)

// ---------------- W transpose: W[64][2048] -> Wt[2048][64] ----------------
__global__ __launch_bounds__(256) void transpose_w_kernel(
    const float* __restrict__ W, float* __restrict__ Wt)
{
    const int idx = blockIdx.x * 256 + threadIdx.x;   // 131072 total
    const int e = idx >> 11;       // expert 0..63
    const int k = idx & 2047;      // k 0..2047
    Wt[k * NEXP + e] = W[idx];
}

// ---------------- GEMM partial: per-lane token, 64-expert accumulator -----
// waves_per_eu(2,4): min 2 keeps the VGPR budget at 256 (R5: natural demand
// 88, no spill of acc[64]); max 4 lets HW run 4 waves/EU when the S=16 grid
// provides 4 blocks/CU -> s_load latency hidden by wave interleaving.
__global__ __launch_bounds__(256)
__attribute__((amdgpu_waves_per_eu(2, 4)))
void gate_partial_kernel(
    const float* __restrict__ inp,
    const float* __restrict__ Wt,      // [KDIM][NEXP]
    float* __restrict__ partial,       // [S][tokens][NEXP]
    int tokens, int kPerSplit)
{
    __shared__ float As[TPB * LDST];   // [token][k] padded, 20 KB

    const int tid     = threadIdx.x;
    const int tokBase = blockIdx.x * TPB;
    const int split   = blockIdx.y;
    const int k0      = split * kPerSplit;

    // staging map: 256 tokens x 16 k per tile; thread t covers row (t>>2)+64p,
    // cols (t&3)*4..+3 (float4). 4 lanes = 64 B contiguous per row.
    const int srow = tid >> 2;          // 0..63
    const int scol = (tid & 3) << 2;    // 0,4,8,12
    const float* aBase = inp + (size_t)tokBase * KDIM + k0;

    float4 stage[4];
    #pragma unroll
    for (int p = 0; p < 4; ++p)
        stage[p] = *(const float4*)(aBase + (size_t)(srow + 64 * p) * KDIM + scol);

    float acc[NEXP];
    #pragma unroll
    for (int e = 0; e < NEXP; ++e) acc[e] = 0.0f;

    const int NT = kPerSplit / BK;
    for (int kt = 0; kt < NT; ++kt) {
        __syncthreads();   // previous tile's reads done
        #pragma unroll
        for (int p = 0; p < 4; ++p)
            *(float4*)&As[(srow + 64 * p) * LDST + scol] = stage[p];
        __syncthreads();
        if (kt + 1 < NT) {
            const int koff = (kt + 1) * BK;
            #pragma unroll
            for (int p = 0; p < 4; ++p)
                stage[p] = *(const float4*)(aBase + (size_t)(srow + 64 * p) * KDIM + koff + scol);
        }
        // W rows for this tile: uniform addresses -> scalar (s_load) pipe
        const float* __restrict__ wTile = Wt + (size_t)(k0 + kt * BK) * NEXP;
        #pragma unroll
        for (int kq = 0; kq < BK / 4; ++kq) {
            const float4 a4 = *(const float4*)&As[tid * LDST + (kq << 2)];
            #pragma unroll
            for (int j = 0; j < 4; ++j) {
                const float a = (j == 0) ? a4.x : (j == 1) ? a4.y : (j == 2) ? a4.z : a4.w;
                const float* __restrict__ wr = wTile + ((kq << 2) + j) * NEXP;
                #pragma unroll
                for (int e = 0; e < NEXP; ++e)
                    acc[e] = fmaf(a, wr[e], acc[e]);
            }
        }
    }

    // write partials: lane owns token tokBase+tid, 64 floats contiguous
    float* p = partial + ((size_t)split * tokens + tokBase + tid) * NEXP;
    #pragma unroll
    for (int e = 0; e < NEXP; e += 4)
        *(float4*)&p[e] = make_float4(acc[e], acc[e + 1], acc[e + 2], acc[e + 3]);
}

// ---------------- reduce over splits + bias + top-2 + softmax -------------
__global__ __launch_bounds__(256) void reduce_topk_kernel(
    const float* __restrict__ partial,
    const float* __restrict__ bias,
    float* __restrict__ out,
    int tokens, int S)
{
    const int tid = threadIdx.x;
    const int tx  = tid & 15;          // experts 4*tx..4*tx+3
    const int ty  = tid >> 4;          // 16 tokens per block
    const int token = blockIdx.x * 16 + ty;
    const int eBase = tx << 2;

    float4 v = make_float4(0.f, 0.f, 0.f, 0.f);
    for (int s = 0; s < S; ++s) {
        const float4 p = *(const float4*)&partial[((size_t)s * tokens + token) * NEXP + eBase];
        v.x += p.x; v.y += p.y; v.z += p.z; v.w += p.w;
    }
    const float4 bv = *(const float4*)&bias[eBase];
    float g[4] = { v.x + bv.x, v.y + bv.y, v.z + bv.z, v.w + bv.w };

    // local top-2 (ascending scan keeps lower index on ties, matching lax.top_k)
    float v1 = g[0]; int i1 = eBase;
    float v2 = -INFINITY; int i2 = -1;
    #pragma unroll
    for (int c = 1; c < 4; ++c) {
        const float vv = g[c];
        const int   ii = eBase + c;
        if (vv > v1)      { v2 = v1; i2 = i1; v1 = vv; i1 = ii; }
        else if (vv > v2) { v2 = vv; i2 = ii; }
    }
    // 16-lane butterfly merge
    #pragma unroll
    for (int m = 1; m <= 8; m <<= 1) {
        const float ov1 = __shfl_xor(v1, m);
        const int   oi1 = __shfl_xor(i1, m);
        const float ov2 = __shfl_xor(v2, m);
        const int   oi2 = __shfl_xor(i2, m);
        const bool aw = (v1 > ov1) || (v1 == ov1 && i1 < oi1);
        const float nv1 = aw ? v1  : ov1;  const int ni1 = aw ? i1  : oi1;
        const float lv  = aw ? ov1 : v1;   const int li  = aw ? oi1 : i1;
        const float sv  = aw ? v2  : ov2;  const int si  = aw ? i2  : oi2;
        const bool sw = (sv > lv) || (sv == lv && si < li);
        v1 = nv1; i1 = ni1;
        v2 = sw ? sv : lv; i2 = sw ? si : li;
    }
    if (tx == 0) {
        const float e2 = expf(v2 - v1);
        const float denom = 1.0f + e2;
        out[2 * token]     = (float)i1;
        out[2 * token + 1] = (float)i2;
        out[tokens * 2 + 2 * token]     = 1.0f / denom;
        out[tokens * 2 + 2 * token + 1] = e2 / denom;
    }
}

extern "C" void kernel_launch(void* const* d_in, const int* in_sizes, int n_in,
                              void* d_out, int out_size, void* d_ws, size_t ws_size,
                              hipStream_t stream) {
    const float* inp  = (const float*)d_in[0];
    const float* W    = (const float*)d_in[1];
    const float* bias = (const float*)d_in[2];
    float* out = (float*)d_out;

    const int tokens = in_sizes[0] / KDIM;   // 16384

    // pick largest split S in {16,8,4,2,1} fitting partials + Wt in d_ws
    int S = 16;
    while (S > 1 &&
           (size_t)S * tokens * NEXP * sizeof(float) + (size_t)KDIM * NEXP * sizeof(float) > ws_size)
        S >>= 1;
    const int kPerSplit = KDIM / S;

    float* partial = (float*)d_ws;
    float* Wt = partial + (size_t)S * tokens * NEXP;

    transpose_w_kernel<<<(NEXP * KDIM) / 256, 256, 0, stream>>>(W, Wt);

    dim3 grid(tokens / TPB, S);
    gate_partial_kernel<<<grid, 256, 0, stream>>>(inp, Wt, partial, tokens, kPerSplit);

    reduce_topk_kernel<<<tokens / 16, 256, 0, stream>>>(partial, bias, out, tokens, S);
}